// Round 8
// baseline (251.776 us; speedup 1.0000x reference)
//
#include <hip/hip_runtime.h>
#include <stdint.h>

typedef unsigned short u16;
typedef __attribute__((ext_vector_type(8))) short short8;    // 8 bf16 (4 VGPRs) MFMA frag
typedef __attribute__((ext_vector_type(4))) float f32x4;     // 16x16 MFMA C/D frag
typedef __attribute__((ext_vector_type(16))) float f32x16;   // 32x32 MFMA C/D frag
typedef __attribute__((ext_vector_type(4))) float float4v;
typedef __attribute__((ext_vector_type(2))) uint32_t u32x2;
typedef __attribute__((ext_vector_type(4))) uint32_t u32x4;

typedef const __attribute__((address_space(1))) void gvoid_t;
typedef __attribute__((address_space(3))) void lvoid_t;

#define N_EMBD 1024
#define NH 16
#define DH 64
#define TSEQ 2048
#define BATCH 4

#define MFMA16 __builtin_amdgcn_mfma_f32_16x16x32_bf16
#define MFMA32 __builtin_amdgcn_mfma_f32_32x32x16_bf16

__device__ __forceinline__ u16 f32_to_bf16(float f) {
  uint32_t x = __builtin_bit_cast(uint32_t, f);
  x = (x + 0x7FFFu + ((x >> 16) & 1u)) >> 16;   // round-to-nearest-even
  return (u16)x;
}

// HW packed f32x2 -> bf16x2 (RNE). No builtin on gfx950 -> inline asm (m240).
__device__ __forceinline__ uint32_t cvtpk(float lo, float hi) {
  uint32_t r;
  asm("v_cvt_pk_bf16_f32 %0, %1, %2" : "=v"(r) : "v"(lo), "v"(hi));
  return r;
}

__device__ __forceinline__ float exp2v(float x) { return __builtin_amdgcn_exp2f(x); }

__device__ __forceinline__ void gload_lds16(const void* g, void* l) {
  __builtin_amdgcn_global_load_lds((gvoid_t*)g, (lvoid_t*)l, 16, 0, 0);
}

// ---------------- elementwise f32 -> bf16 ----------------
__global__ void cvt_kernel(const float* __restrict__ in, u16* __restrict__ out, int n4) {
  int i = blockIdx.x * blockDim.x + threadIdx.x;
  if (i < n4) {
    float4v v = *(const float4v*)(in + (size_t)i * 4);
    u32x2 o;
    o[0] = cvtpk(v[0], v[1]);
    o[1] = cvtpk(v[2], v[3]);
    *(u32x2*)(out + (size_t)i * 4) = o;
  }
}

// ---------------- fused weight transposes f32->bf16 (both weights, 1 launch) ----
__global__ void transpose2_bf16(const float* __restrict__ wqkv, u16* __restrict__ wqkvT,
                                const float* __restrict__ wout, u16* __restrict__ woutT) {
  __shared__ u16 tile[32][33];
  const int y = blockIdx.y;
  const float* in;
  u16* out;
  int C, c0;
  if (y < 96) { in = wqkv; out = wqkvT; C = 3072; c0 = y * 32; }
  else        { in = wout; out = woutT; C = 1024; c0 = (y - 96) * 32; }
  const int r0 = blockIdx.x * 32;                     // R = 1024 for both
  const int tx = threadIdx.x & 31, ty = threadIdx.x >> 5;
#pragma unroll
  for (int i = 0; i < 4; i++)
    tile[ty + i * 8][tx] = f32_to_bf16(in[(size_t)(r0 + ty + i * 8) * C + c0 + tx]);
  __syncthreads();
#pragma unroll
  for (int i = 0; i < 4; i++)
    out[(size_t)(c0 + ty + i * 8) * 1024 + r0 + tx] = tile[tx][ty + i * 8];
}

// ---------------- 128x128 GEMM, A[M][K] bf16, Bt[N][K] bf16 ----------------
// T1 XCD-aware swizzle (nwg % 8 == 0 for both uses).
// EPI==0: C f32 linear.
// EPI==1: scatter Q,K to [B,H,T,D] bf16 (Q pre-scaled); V direct to V^T [B,H,D,T].
template <int EPI>
__global__ __launch_bounds__(256)
void gemm128(const u16* __restrict__ A, const u16* __restrict__ Bt,
             float* __restrict__ Cf, u16* __restrict__ Qb, u16* __restrict__ Kb,
             u16* __restrict__ Vt, int M, int N, int K) {
  __shared__ u16 sA[128 * 64];
  __shared__ u16 sB[128 * 64];
  const int tid = threadIdx.x;
  const int lane = tid & 63, w = tid >> 6;
  const int wm = w >> 1, wn = w & 1;
  const int l15 = lane & 15, lg = lane >> 4;
  // XCD swizzle: consecutive work chunks land on one XCD's L2 (T1, m192)
  const int nwg = gridDim.x * gridDim.y;
  int flat = blockIdx.y * gridDim.x + blockIdx.x;
  flat = (flat & 7) * (nwg >> 3) + (flat >> 3);
  const int m0 = (flat % gridDim.x) * 128;
  const int n0 = (flat / gridDim.x) * 128;
  f32x4 acc[4][4] = {};
  const int srow = tid >> 3, scb = tid & 7;

  auto stage = [&](int k0) {
#pragma unroll
    for (int i = 0; i < 4; i++) {
      int row = i * 32 + srow;
      int cb = scb ^ (row & 7);                      // pre-swizzled SOURCE (rule #21)
      gload_lds16(A + (size_t)(m0 + row) * K + k0 + cb * 8, sA + i * 2048 + w * 512);
      gload_lds16(Bt + (size_t)(n0 + row) * K + k0 + cb * 8, sB + i * 2048 + w * 512);
    }
  };

  stage(0);
  for (int k0 = 0; k0 < K; k0 += 64) {
    __syncthreads();                                  // staging for k0 visible
    short8 af[4][2], bf[4][2];
#pragma unroll
    for (int mi = 0; mi < 4; mi++)
#pragma unroll
      for (int kk = 0; kk < 2; kk++) {
        int ra = wm * 64 + mi * 16 + l15;
        af[mi][kk] = *(const short8*)(sA + ra * 64 + ((kk * 4 + lg) ^ (ra & 7)) * 8);
        int rb = wn * 64 + mi * 16 + l15;
        bf[mi][kk] = *(const short8*)(sB + rb * 64 + ((kk * 4 + lg) ^ (rb & 7)) * 8);
      }
    if (k0 + 64 < K) {
      __syncthreads();                                // all frag reads done
      stage(k0 + 64);                                 // prefetch overlaps MFMA
    }
#pragma unroll
    for (int kk = 0; kk < 2; kk++)
#pragma unroll
      for (int mi = 0; mi < 4; mi++)
#pragma unroll
        for (int ni = 0; ni < 4; ni++)
          acc[mi][ni] = MFMA16(af[mi][kk], bf[ni][kk], acc[mi][ni], 0, 0, 0);
  }

#pragma unroll
  for (int mi = 0; mi < 4; mi++)
#pragma unroll
    for (int ni = 0; ni < 4; ni++) {
      const int mb = m0 + wm * 64 + mi * 16 + lg * 4;   // rows mb..mb+3 (t 4-aligned)
      const int n = n0 + wn * 64 + ni * 16 + l15;       // C col = lane&15
      if (EPI == 0) {
#pragma unroll
        for (int r = 0; r < 4; r++)
          Cf[(size_t)(mb + r) * N + n] = acc[mi][ni][r];
      } else {
        const int b = mb >> 11, t = mb & 2047;
        const int sec = n >> 10, c = n & 1023;          // sec uniform across wave
        const int h = c >> 6, d = c & 63;
        if (sec == 2) {
          // V^T [B,H,D,T]: 4 consecutive t per lane -> one 8B packed store
          u32x2 pkd;
          pkd[0] = cvtpk(acc[mi][ni][0], acc[mi][ni][1]);
          pkd[1] = cvtpk(acc[mi][ni][2], acc[mi][ni][3]);
          *(u32x2*)(Vt + ((size_t)(b * NH + h) * DH + d) * TSEQ + t) = pkd;
        } else {
          u16* dst = (sec == 0) ? Qb : Kb;
          const float sc = (sec == 0) ? 0.1803368801111204f : 1.0f;  // 1/8 * log2e
#pragma unroll
          for (int r = 0; r < 4; r++)
            dst[((size_t)(b * NH + h) * TSEQ + t + r) * DH + d] = f32_to_bf16(acc[mi][ni][r] * sc);
        }
      }
    }
}

// ---------------- causal flash attention, 32x32 MFMA, P fully in-register ----
// 1D grid of 1024 blocks (longest-first): qt = 15 - id/64, bh = id & 63.
// Block owns 128 q-rows; wave w owns 32 contiguous q at q0 = qb0 + w*32.
// S^T = mfma32(K,Q): lane(l31,b5) holds S[k=kb*32+(reg&3)+8*(reg>>2)+4*b5][q=q0+l31].
// P redistributed to B-frag via cvt_pk + shfl_xor(32) + cndmask (T12) - no LDS.
// O^T = mfma32(V^T,P): lane holds O[d=db*32+row(reg,b5)][q=q0+l31].
__global__ __launch_bounds__(256)
void attn_kernel(const u16* __restrict__ Q, const u16* __restrict__ K,
                 const u16* __restrict__ Vt, u16* __restrict__ AO) {
  __shared__ u16 sK[2][64 * 64];
  __shared__ u16 sV[2][64 * 64];
  const int tid = threadIdx.x;
  const int lane = tid & 63, w = tid >> 6;
  const int l31 = lane & 31;           // q index within wave tile
  const int b5 = lane >> 5;            // lane half
  const int id = blockIdx.x;
  const int qt = 15 - (id >> 6);
  const int bh = id & 63;
  const int qb0 = qt * 128;
  const size_t bh_off = (size_t)bh * TSEQ * DH;
  const int q0 = qb0 + w * 32;

  // Q B-frags (Q pre-scaled by 0.125*log2e): bq[ks] = Q[q0+l31][ks*16+b5*8 ..+7]
  short8 bq[4];
#pragma unroll
  for (int ks = 0; ks < 4; ks++)
    bq[ks] = *(const short8*)(Q + bh_off + (size_t)(q0 + l31) * DH + ks * 16 + b5 * 8);

  f32x16 accO[2] = {};                 // accO[db]: O^T fragment (d block db*32)
  float mrow = -3e38f, lrow = 0.f;

  const int srow = tid >> 3, scb = tid & 7;

  auto stage = [&](int it, int buf) {
    const int k0 = it * 64;
    u16* dK = sK[buf];
    u16* dV = sV[buf];
#pragma unroll
    for (int i = 0; i < 2; i++) {
      int r = i * 32 + srow;
      int cb = scb ^ (r & 7);
      gload_lds16(K + bh_off + (size_t)(k0 + r) * DH + cb * 8, dK + i * 2048 + w * 512);
      gload_lds16(Vt + bh_off + (size_t)r * TSEQ + k0 + cb * 8, dV + i * 2048 + w * 512);
    }
  };

  const int ntiles = 2 * qt + 2;
  stage(0, 0);
  for (int it = 0; it < ntiles; ++it) {
    const int k0 = it * 64;
    __syncthreads();                       // stage(it) visible; prev-tile reads done
    const int cur = it & 1;
    if (it + 1 < ntiles) stage(it + 1, cur ^ 1);   // prefetch overlaps this tile
    if (k0 > q0 + 31) continue;            // wave fully done (causal); barriers still met

    const u16* cK = sK[cur];
    const u16* cV = sV[cur];

    // K A-frags: ak[kb][ks]: K[kb*32+l31][ks*16 + b5*8 ..+7] (swizzled)
    short8 ak[2][4];
#pragma unroll
    for (int kb = 0; kb < 2; kb++)
#pragma unroll
      for (int ks = 0; ks < 4; ks++) {
        int rk = kb * 32 + l31;
        ak[kb][ks] = *(const short8*)(cK + rk * 64 + (((ks * 2 + b5) ^ (rk & 7)) * 8));
      }

    // S^T = K·Q
    f32x16 accS[2] = {};
    __builtin_amdgcn_s_setprio(1);
#pragma unroll
    for (int ks = 0; ks < 4; ks++)
#pragma unroll
      for (int kb = 0; kb < 2; kb++)
        accS[kb] = MFMA32(ak[kb][ks], bq[ks], accS[kb], 0, 0, 0);
    __builtin_amdgcn_s_setprio(0);

    // causal mask (single diagonal tile per wave)
    if (k0 + 63 > q0) {
#pragma unroll
      for (int kb = 0; kb < 2; kb++)
#pragma unroll
        for (int reg = 0; reg < 16; reg++) {
          int kg = k0 + kb * 32 + (reg & 3) + 8 * (reg >> 2) + 4 * b5;
          if (kg > q0 + l31) accS[kb][reg] = -1e30f;
        }
    }

    // per-q max: 31 fmax + 1 shfl (k spread over regs and b5 only)
    float mt = fmaxf(accS[0][0], accS[0][1]);
#pragma unroll
    for (int reg = 2; reg < 16; reg++) mt = fmaxf(mt, accS[0][reg]);
#pragma unroll
    for (int reg = 0; reg < 16; reg++) mt = fmaxf(mt, accS[1][reg]);
    mt = fmaxf(mt, __shfl_xor(mt, 32));

    float mnew = mrow;
    // T13 defer-max: skip rescale while max grows by <= 8 (P bounded by 2^8)
    if (!__all(mt <= mrow + 8.0f)) {
      mnew = fmaxf(mrow, mt);
      const float alpha = exp2v(mrow - mnew);
      mrow = mnew;
      lrow *= alpha;
#pragma unroll
      for (int db = 0; db < 2; db++)
#pragma unroll
        for (int reg = 0; reg < 16; reg++) accO[db][reg] *= alpha;
    }

    // exp2 + row-sum + pack to bf16 pairs: pk[kb][r1][d] = P(k=kb*32+8*r1+4*b5+2d+{0,1})
    uint32_t pk[2][4][2];
    float rsum = 0.f;
#pragma unroll
    for (int kb = 0; kb < 2; kb++)
#pragma unroll
      for (int r1 = 0; r1 < 4; r1++) {
        float p0 = exp2v(accS[kb][r1 * 4 + 0] - mnew);
        float p1 = exp2v(accS[kb][r1 * 4 + 1] - mnew);
        float p2 = exp2v(accS[kb][r1 * 4 + 2] - mnew);
        float p3 = exp2v(accS[kb][r1 * 4 + 3] - mnew);
        rsum += (p0 + p1) + (p2 + p3);
        pk[kb][r1][0] = cvtpk(p0, p1);
        pk[kb][r1][1] = cvtpk(p2, p3);
      }
    rsum += __shfl_xor(rsum, 32);
    lrow += rsum;

    // redistribute P to B-frag layout: bp[ks] slot s = pk[ks>>1][(ks&1)*2+b5_t][s&1]
    // pulled from lane half s>>1 (own or shfl_xor(32)); cndmask keeps reg idx static.
    short8 bp[4];
#pragma unroll
    for (int ks = 0; ks < 4; ks++) {
      const int kb = ks >> 1, base = (ks & 1) * 2;
      uint32_t A0 = b5 ? pk[kb][base + 1][0] : pk[kb][base][0];
      uint32_t A1 = b5 ? pk[kb][base + 1][1] : pk[kb][base][1];
      uint32_t B0 = b5 ? pk[kb][base][0] : pk[kb][base + 1][0];
      uint32_t B1 = b5 ? pk[kb][base][1] : pk[kb][base + 1][1];
      uint32_t Bs0 = __shfl_xor(B0, 32);
      uint32_t Bs1 = __shfl_xor(B1, 32);
      u32x4 v;
      v[0] = b5 ? Bs0 : A0;
      v[1] = b5 ? Bs1 : A1;
      v[2] = b5 ? A0 : Bs0;
      v[3] = b5 ? A1 : Bs1;
      bp[ks] = __builtin_bit_cast(short8, v);
    }

    // V^T A-frags + PV: O^T += V^T · P
    short8 av[2][4];
#pragma unroll
    for (int db = 0; db < 2; db++)
#pragma unroll
      for (int ks = 0; ks < 4; ks++) {
        int rv = db * 32 + l31;
        av[db][ks] = *(const short8*)(cV + rv * 64 + (((ks * 2 + b5) ^ (rv & 7)) * 8));
      }
    __builtin_amdgcn_s_setprio(1);
#pragma unroll
    for (int ks = 0; ks < 4; ks++)
#pragma unroll
      for (int db = 0; db < 2; db++)
        accO[db] = MFMA32(av[db][ks], bp[ks], accO[db], 0, 0, 0);
    __builtin_amdgcn_s_setprio(0);
  }

  // epilogue: lane writes q = q0+l31, d = db*32 + 8*r1 + 4*b5 + {0..3} (8B stores)
  const int b = bh >> 4, h = bh & 15;
  const int t = q0 + l31;
  const float inv = 1.0f / lrow;
  u16* orow = AO + ((size_t)b * TSEQ + t) * N_EMBD + h * 64 + 4 * b5;
#pragma unroll
  for (int db = 0; db < 2; db++)
#pragma unroll
    for (int r1 = 0; r1 < 4; r1++) {
      u32x2 pkd;
      pkd[0] = cvtpk(accO[db][r1 * 4 + 0] * inv, accO[db][r1 * 4 + 1] * inv);
      pkd[1] = cvtpk(accO[db][r1 * 4 + 2] * inv, accO[db][r1 * 4 + 3] * inv);
      *(u32x2*)(orow + db * 32 + r1 * 8) = pkd;
    }
}

extern "C" void kernel_launch(void* const* d_in, const int* in_sizes, int n_in,
                              void* d_out, int out_size, void* d_ws, size_t ws_size,
                              hipStream_t stream) {
  const float* x = (const float*)d_in[0];
  const float* w_qkv = (const float*)d_in[1];
  const float* w_out = (const float*)d_in[2];
  float* out = (float*)d_out;
  char* ws = (char*)d_ws;
  const size_t MB = 1 << 20;
  u16* xb    = (u16*)(ws);             // 16MB, reused as AO after gemm1
  u16* wqkvT = (u16*)(ws + 16 * MB);   // 6MB
  u16* woutT = (u16*)(ws + 22 * MB);   // 2MB
  u16* Qb    = (u16*)(ws + 24 * MB);   // 16MB
  u16* Kb    = (u16*)(ws + 40 * MB);   // 16MB
  u16* Vt    = (u16*)(ws + 56 * MB);   // 16MB (V^T written directly by gemm1)
  u16* AO    = xb;

  cvt_kernel<<<8192, 256, 0, stream>>>(x, xb, (BATCH * TSEQ * N_EMBD) / 4);
  transpose2_bf16<<<dim3(32, 128), 256, 0, stream>>>(w_qkv, wqkvT, w_out, woutT);
  gemm128<1><<<dim3(64, 24), 256, 0, stream>>>(xb, wqkvT, nullptr, Qb, Kb, Vt,
                                               BATCH * TSEQ, 3 * N_EMBD, N_EMBD);
  attn_kernel<<<1024, 256, 0, stream>>>(Qb, Kb, Vt, AO);
  gemm128<0><<<dim3(64, 8), 256, 0, stream>>>(AO, woutT, out, nullptr, nullptr, nullptr,
                                              BATCH * TSEQ, N_EMBD, N_EMBD);
}

// Round 9
// 238.779 us; speedup vs baseline: 1.0544x; 1.0544x over previous
//
#include <hip/hip_runtime.h>
#include <stdint.h>

typedef unsigned short u16;
typedef __attribute__((ext_vector_type(8))) short short8;    // 8 bf16 (4 VGPRs) MFMA frag
typedef __attribute__((ext_vector_type(4))) float f32x4;     // 16x16 MFMA C/D frag
typedef __attribute__((ext_vector_type(16))) float f32x16;   // 32x32 MFMA C/D frag
typedef __attribute__((ext_vector_type(4))) float float4v;
typedef __attribute__((ext_vector_type(2))) uint32_t u32x2;
typedef __attribute__((ext_vector_type(4))) uint32_t u32x4;

typedef const __attribute__((address_space(1))) void gvoid_t;
typedef __attribute__((address_space(3))) void lvoid_t;

#define N_EMBD 1024
#define NH 16
#define DH 64
#define TSEQ 2048
#define BATCH 4

#define MFMA16 __builtin_amdgcn_mfma_f32_16x16x32_bf16
#define MFMA32 __builtin_amdgcn_mfma_f32_32x32x16_bf16

__device__ __forceinline__ u16 f32_to_bf16(float f) {
  uint32_t x = __builtin_bit_cast(uint32_t, f);
  x = (x + 0x7FFFu + ((x >> 16) & 1u)) >> 16;   // round-to-nearest-even
  return (u16)x;
}

// HW packed f32x2 -> bf16x2 (RNE). No builtin on gfx950 -> inline asm (m240).
__device__ __forceinline__ uint32_t cvtpk(float lo, float hi) {
  uint32_t r;
  asm("v_cvt_pk_bf16_f32 %0, %1, %2" : "=v"(r) : "v"(lo), "v"(hi));
  return r;
}

// 3-input max, single VOP3 instruction (T17)
__device__ __forceinline__ float max3(float a, float b, float c) {
  float r;
  asm("v_max3_f32 %0, %1, %2, %3" : "=v"(r) : "v"(a), "v"(b), "v"(c));
  return r;
}

__device__ __forceinline__ float exp2v(float x) { return __builtin_amdgcn_exp2f(x); }

__device__ __forceinline__ void gload_lds16(const void* g, void* l) {
  __builtin_amdgcn_global_load_lds((gvoid_t*)g, (lvoid_t*)l, 16, 0, 0);
}

// ---------------- elementwise f32 -> bf16 ----------------
__global__ void cvt_kernel(const float* __restrict__ in, u16* __restrict__ out, int n4) {
  int i = blockIdx.x * blockDim.x + threadIdx.x;
  if (i < n4) {
    float4v v = *(const float4v*)(in + (size_t)i * 4);
    u32x2 o;
    o[0] = cvtpk(v[0], v[1]);
    o[1] = cvtpk(v[2], v[3]);
    *(u32x2*)(out + (size_t)i * 4) = o;
  }
}

// ---------------- fused weight transposes f32->bf16 (both weights, 1 launch) ----
__global__ void transpose2_bf16(const float* __restrict__ wqkv, u16* __restrict__ wqkvT,
                                const float* __restrict__ wout, u16* __restrict__ woutT) {
  __shared__ u16 tile[32][33];
  const int y = blockIdx.y;
  const float* in;
  u16* out;
  int C, c0;
  if (y < 96) { in = wqkv; out = wqkvT; C = 3072; c0 = y * 32; }
  else        { in = wout; out = woutT; C = 1024; c0 = (y - 96) * 32; }
  const int r0 = blockIdx.x * 32;                     // R = 1024 for both
  const int tx = threadIdx.x & 31, ty = threadIdx.x >> 5;
#pragma unroll
  for (int i = 0; i < 4; i++)
    tile[ty + i * 8][tx] = f32_to_bf16(in[(size_t)(r0 + ty + i * 8) * C + c0 + tx]);
  __syncthreads();
#pragma unroll
  for (int i = 0; i < 4; i++)
    out[(size_t)(c0 + ty + i * 8) * 1024 + r0 + tx] = tile[tx][ty + i * 8];
}

// ---------------- 128x128 GEMM, A[M][K] bf16, Bt[N][K] bf16 ----------------
// Direct blockIdx mapping: inputs are L3-resident, XCD swizzle HURTS here
// (measured r8: n-panel chunking -> 192MB L2-miss fetch, gemm1 52->78us).
// EPI==0: C f32 linear.
// EPI==1: scatter Q,K to [B,H,T,D] bf16 (Q pre-scaled); V direct to V^T [B,H,D,T].
template <int EPI>
__global__ __launch_bounds__(256)
void gemm128(const u16* __restrict__ A, const u16* __restrict__ Bt,
             float* __restrict__ Cf, u16* __restrict__ Qb, u16* __restrict__ Kb,
             u16* __restrict__ Vt, int M, int N, int K) {
  __shared__ u16 sA[128 * 64];
  __shared__ u16 sB[128 * 64];
  const int tid = threadIdx.x;
  const int lane = tid & 63, w = tid >> 6;
  const int wm = w >> 1, wn = w & 1;
  const int l15 = lane & 15, lg = lane >> 4;
  const int m0 = blockIdx.x * 128, n0 = blockIdx.y * 128;
  f32x4 acc[4][4] = {};
  const int srow = tid >> 3, scb = tid & 7;

  auto stage = [&](int k0) {
#pragma unroll
    for (int i = 0; i < 4; i++) {
      int row = i * 32 + srow;
      int cb = scb ^ (row & 7);                      // pre-swizzled SOURCE (rule #21)
      gload_lds16(A + (size_t)(m0 + row) * K + k0 + cb * 8, sA + i * 2048 + w * 512);
      gload_lds16(Bt + (size_t)(n0 + row) * K + k0 + cb * 8, sB + i * 2048 + w * 512);
    }
  };

  stage(0);
  for (int k0 = 0; k0 < K; k0 += 64) {
    __syncthreads();                                  // staging for k0 visible
    short8 af[4][2], bf[4][2];
#pragma unroll
    for (int mi = 0; mi < 4; mi++)
#pragma unroll
      for (int kk = 0; kk < 2; kk++) {
        int ra = wm * 64 + mi * 16 + l15;
        af[mi][kk] = *(const short8*)(sA + ra * 64 + ((kk * 4 + lg) ^ (ra & 7)) * 8);
        int rb = wn * 64 + mi * 16 + l15;
        bf[mi][kk] = *(const short8*)(sB + rb * 64 + ((kk * 4 + lg) ^ (rb & 7)) * 8);
      }
    if (k0 + 64 < K) {
      __syncthreads();                                // all frag reads done
      stage(k0 + 64);                                 // prefetch overlaps MFMA
    }
#pragma unroll
    for (int kk = 0; kk < 2; kk++)
#pragma unroll
      for (int mi = 0; mi < 4; mi++)
#pragma unroll
        for (int ni = 0; ni < 4; ni++)
          acc[mi][ni] = MFMA16(af[mi][kk], bf[ni][kk], acc[mi][ni], 0, 0, 0);
  }

#pragma unroll
  for (int mi = 0; mi < 4; mi++)
#pragma unroll
    for (int ni = 0; ni < 4; ni++) {
      const int mb = m0 + wm * 64 + mi * 16 + lg * 4;   // rows mb..mb+3 (t 4-aligned)
      const int n = n0 + wn * 64 + ni * 16 + l15;       // C col = lane&15
      if (EPI == 0) {
#pragma unroll
        for (int r = 0; r < 4; r++)
          Cf[(size_t)(mb + r) * N + n] = acc[mi][ni][r];
      } else {
        const int b = mb >> 11, t = mb & 2047;
        const int sec = n >> 10, c = n & 1023;          // sec uniform across wave
        const int h = c >> 6, d = c & 63;
        if (sec == 2) {
          // V^T [B,H,D,T]: 4 consecutive t per lane -> one 8B packed store
          u32x2 pkd;
          pkd[0] = cvtpk(acc[mi][ni][0], acc[mi][ni][1]);
          pkd[1] = cvtpk(acc[mi][ni][2], acc[mi][ni][3]);
          *(u32x2*)(Vt + ((size_t)(b * NH + h) * DH + d) * TSEQ + t) = pkd;
        } else {
          u16* dst = (sec == 0) ? Qb : Kb;
          const float sc = (sec == 0) ? 0.1803368801111204f : 1.0f;  // 1/8 * log2e
#pragma unroll
          for (int r = 0; r < 4; r++)
            dst[((size_t)(b * NH + h) * TSEQ + t + r) * DH + d] = f32_to_bf16(acc[mi][ni][r] * sc);
        }
      }
    }
}

// ---------------- causal flash attention, 32x32 MFMA, P fully in-register ----
// 1D grid of 1024 blocks (longest-first): qt = 15 - id/64, bh = id & 63.
// Block owns 128 q-rows; wave w owns 32 contiguous q at q0 = qb0 + w*32.
// S^T = mfma32(K,Q): lane(l31,b5) holds S[k=kb*32+(reg&3)+8*(reg>>2)+4*b5][q=q0+l31].
// P redistributed to B-frag via cvt_pk + shfl_xor(32) + cndmask (T12) - no LDS.
// O^T = mfma32(V^T,P): lane holds O[d=db*32+row(reg,b5)][q=q0+l31].
__global__ __launch_bounds__(256)
void attn_kernel(const u16* __restrict__ Q, const u16* __restrict__ K,
                 const u16* __restrict__ Vt, u16* __restrict__ AO) {
  __shared__ u16 sK[2][64 * 64];
  __shared__ u16 sV[2][64 * 64];
  const int tid = threadIdx.x;
  const int lane = tid & 63, w = tid >> 6;
  const int l31 = lane & 31;           // q index within wave tile
  const int b5 = lane >> 5;            // lane half
  const int id = blockIdx.x;
  const int qt = 15 - (id >> 6);
  const int bh = id & 63;
  const int qb0 = qt * 128;
  const size_t bh_off = (size_t)bh * TSEQ * DH;
  const int q0 = qb0 + w * 32;

  // Q B-frags (Q pre-scaled by 0.125*log2e): bq[ks] = Q[q0+l31][ks*16+b5*8 ..+7]
  short8 bq[4];
#pragma unroll
  for (int ks = 0; ks < 4; ks++)
    bq[ks] = *(const short8*)(Q + bh_off + (size_t)(q0 + l31) * DH + ks * 16 + b5 * 8);

  f32x16 accO[2] = {};                 // accO[db]: O^T fragment (d block db*32)
  float mrow = -3e38f, lrow = 0.f;

  const int srow = tid >> 3, scb = tid & 7;

  auto stage = [&](int it, int buf) {
    const int k0 = it * 64;
    u16* dK = sK[buf];
    u16* dV = sV[buf];
#pragma unroll
    for (int i = 0; i < 2; i++) {
      int r = i * 32 + srow;
      int cb = scb ^ (r & 7);
      gload_lds16(K + bh_off + (size_t)(k0 + r) * DH + cb * 8, dK + i * 2048 + w * 512);
      gload_lds16(Vt + bh_off + (size_t)r * TSEQ + k0 + cb * 8, dV + i * 2048 + w * 512);
    }
  };

  const int ntiles = 2 * qt + 2;
  stage(0, 0);
  for (int it = 0; it < ntiles; ++it) {
    const int k0 = it * 64;
    __syncthreads();                       // stage(it) visible; prev-tile reads done
    const int cur = it & 1;
    if (it + 1 < ntiles) stage(it + 1, cur ^ 1);   // prefetch overlaps this tile
    if (k0 > q0 + 31) continue;            // wave fully done (causal); barriers still met

    const u16* cK = sK[cur];
    const u16* cV = sV[cur];

    // K A-frags: ak[kb][ks]: K[kb*32+l31][ks*16 + b5*8 ..+7] (swizzled)
    short8 ak[2][4];
#pragma unroll
    for (int kb = 0; kb < 2; kb++)
#pragma unroll
      for (int ks = 0; ks < 4; ks++) {
        int rk = kb * 32 + l31;
        ak[kb][ks] = *(const short8*)(cK + rk * 64 + (((ks * 2 + b5) ^ (rk & 7)) * 8));
      }

    // S^T = K·Q
    f32x16 accS[2] = {};
    __builtin_amdgcn_s_setprio(1);
#pragma unroll
    for (int ks = 0; ks < 4; ks++)
#pragma unroll
      for (int kb = 0; kb < 2; kb++)
        accS[kb] = MFMA32(ak[kb][ks], bq[ks], accS[kb], 0, 0, 0);
    __builtin_amdgcn_s_setprio(0);

    // causal mask (single diagonal tile per wave)
    if (k0 + 63 > q0) {
#pragma unroll
      for (int kb = 0; kb < 2; kb++)
#pragma unroll
        for (int reg = 0; reg < 16; reg++) {
          int kg = k0 + kb * 32 + (reg & 3) + 8 * (reg >> 2) + 4 * b5;
          if (kg > q0 + l31) accS[kb][reg] = -1e30f;
        }
    }

    // per-q max: depth-4 v_max3 tree (17 instrs, ~16cy latency vs 31-op serial chain)
    float m00 = max3(accS[0][0], accS[0][1], accS[0][2]);
    float m01 = max3(accS[0][3], accS[0][4], accS[0][5]);
    float m02 = max3(accS[0][6], accS[0][7], accS[0][8]);
    float m03 = max3(accS[0][9], accS[0][10], accS[0][11]);
    float m04 = max3(accS[0][12], accS[0][13], accS[0][14]);
    float m10 = max3(accS[0][15], accS[1][0], accS[1][1]);
    float m11 = max3(accS[1][2], accS[1][3], accS[1][4]);
    float m12 = max3(accS[1][5], accS[1][6], accS[1][7]);
    float m13 = max3(accS[1][8], accS[1][9], accS[1][10]);
    float m14 = max3(accS[1][11], accS[1][12], accS[1][13]);
    float n0_ = max3(m00, m01, m02);
    float n1_ = max3(m03, m04, m10);
    float n2_ = max3(m11, m12, m13);
    float n3_ = max3(m14, accS[1][14], accS[1][15]);
    float mt = fmaxf(fmaxf(n0_, n1_), fmaxf(n2_, n3_));
    mt = fmaxf(mt, __shfl_xor(mt, 32));

    float mnew = mrow;
    // T13 defer-max: skip rescale while max grows by <= 8 (P bounded by 2^8)
    if (!__all(mt <= mrow + 8.0f)) {
      mnew = fmaxf(mrow, mt);
      const float alpha = exp2v(mrow - mnew);
      mrow = mnew;
      lrow *= alpha;
#pragma unroll
      for (int db = 0; db < 2; db++)
#pragma unroll
        for (int reg = 0; reg < 16; reg++) accO[db][reg] *= alpha;
    }

    // exp2 + row-sum + pack to bf16 pairs: pk[kb][r1][d] = P(k=kb*32+8*r1+4*b5+2d+{0,1})
    uint32_t pk[2][4][2];
    float ps[8];
#pragma unroll
    for (int kb = 0; kb < 2; kb++)
#pragma unroll
      for (int r1 = 0; r1 < 4; r1++) {
        float p0 = exp2v(accS[kb][r1 * 4 + 0] - mnew);
        float p1 = exp2v(accS[kb][r1 * 4 + 1] - mnew);
        float p2 = exp2v(accS[kb][r1 * 4 + 2] - mnew);
        float p3 = exp2v(accS[kb][r1 * 4 + 3] - mnew);
        ps[kb * 4 + r1] = (p0 + p1) + (p2 + p3);
        pk[kb][r1][0] = cvtpk(p0, p1);
        pk[kb][r1][1] = cvtpk(p2, p3);
      }
    float rsum = ((ps[0] + ps[1]) + (ps[2] + ps[3])) + ((ps[4] + ps[5]) + (ps[6] + ps[7]));
    rsum += __shfl_xor(rsum, 32);
    lrow += rsum;

    // redistribute P to B-frag layout: bp[ks] slot s = pk[ks>>1][(ks&1)*2+b5_t][s&1]
    // pulled from lane half s>>1 (own or shfl_xor(32)); cndmask keeps reg idx static.
    short8 bp[4];
#pragma unroll
    for (int ks = 0; ks < 4; ks++) {
      const int kb = ks >> 1, base = (ks & 1) * 2;
      uint32_t A0 = b5 ? pk[kb][base + 1][0] : pk[kb][base][0];
      uint32_t A1 = b5 ? pk[kb][base + 1][1] : pk[kb][base][1];
      uint32_t B0 = b5 ? pk[kb][base][0] : pk[kb][base + 1][0];
      uint32_t B1 = b5 ? pk[kb][base][1] : pk[kb][base + 1][1];
      uint32_t Bs0 = __shfl_xor(B0, 32);
      uint32_t Bs1 = __shfl_xor(B1, 32);
      u32x4 v;
      v[0] = b5 ? Bs0 : A0;
      v[1] = b5 ? Bs1 : A1;
      v[2] = b5 ? A0 : Bs0;
      v[3] = b5 ? A1 : Bs1;
      bp[ks] = __builtin_bit_cast(short8, v);
    }

    // V^T A-frags + PV: O^T += V^T · P
    short8 av[2][4];
#pragma unroll
    for (int db = 0; db < 2; db++)
#pragma unroll
      for (int ks = 0; ks < 4; ks++) {
        int rv = db * 32 + l31;
        av[db][ks] = *(const short8*)(cV + rv * 64 + (((ks * 2 + b5) ^ (rv & 7)) * 8));
      }
    __builtin_amdgcn_s_setprio(1);
#pragma unroll
    for (int ks = 0; ks < 4; ks++)
#pragma unroll
      for (int db = 0; db < 2; db++)
        accO[db] = MFMA32(av[db][ks], bp[ks], accO[db], 0, 0, 0);
    __builtin_amdgcn_s_setprio(0);
  }

  // epilogue: lane writes q = q0+l31, d = db*32 + 8*r1 + 4*b5 + {0..3} (8B stores)
  const int b = bh >> 4, h = bh & 15;
  const int t = q0 + l31;
  const float inv = 1.0f / lrow;
  u16* orow = AO + ((size_t)b * TSEQ + t) * N_EMBD + h * 64 + 4 * b5;
#pragma unroll
  for (int db = 0; db < 2; db++)
#pragma unroll
    for (int r1 = 0; r1 < 4; r1++) {
      u32x2 pkd;
      pkd[0] = cvtpk(accO[db][r1 * 4 + 0] * inv, accO[db][r1 * 4 + 1] * inv);
      pkd[1] = cvtpk(accO[db][r1 * 4 + 2] * inv, accO[db][r1 * 4 + 3] * inv);
      *(u32x2*)(orow + db * 32 + r1 * 8) = pkd;
    }
}

extern "C" void kernel_launch(void* const* d_in, const int* in_sizes, int n_in,
                              void* d_out, int out_size, void* d_ws, size_t ws_size,
                              hipStream_t stream) {
  const float* x = (const float*)d_in[0];
  const float* w_qkv = (const float*)d_in[1];
  const float* w_out = (const float*)d_in[2];
  float* out = (float*)d_out;
  char* ws = (char*)d_ws;
  const size_t MB = 1 << 20;
  u16* xb    = (u16*)(ws);             // 16MB, reused as AO after gemm1
  u16* wqkvT = (u16*)(ws + 16 * MB);   // 6MB
  u16* woutT = (u16*)(ws + 22 * MB);   // 2MB
  u16* Qb    = (u16*)(ws + 24 * MB);   // 16MB
  u16* Kb    = (u16*)(ws + 40 * MB);   // 16MB
  u16* Vt    = (u16*)(ws + 56 * MB);   // 16MB (V^T written directly by gemm1)
  u16* AO    = xb;

  cvt_kernel<<<8192, 256, 0, stream>>>(x, xb, (BATCH * TSEQ * N_EMBD) / 4);
  transpose2_bf16<<<dim3(32, 128), 256, 0, stream>>>(w_qkv, wqkvT, w_out, woutT);
  gemm128<1><<<dim3(64, 24), 256, 0, stream>>>(xb, wqkvT, nullptr, Qb, Kb, Vt,
                                               BATCH * TSEQ, 3 * N_EMBD, N_EMBD);
  attn_kernel<<<1024, 256, 0, stream>>>(Qb, Kb, Vt, AO);
  gemm128<0><<<dim3(64, 8), 256, 0, stream>>>(AO, woutT, out, nullptr, nullptr, nullptr,
                                              BATCH * TSEQ, N_EMBD, N_EMBD);
}